// Round 2
// baseline (659.964 us; speedup 1.0000x reference)
//
#include <hip/hip_runtime.h>

// DinkNet: 2x GraphConv(512->128) encoders (clean + row-permuted) + PReLU,
// folded MLP (rowsum trick) -> logit[2N].
//
// Identities:  (x[perm])@W = (x@W)[perm]  -> one GEMM
//              (z@mlpW+mlpb).sum(1) = z . rowsum(mlpW) + sum(mlpb)
// Round 5: device-scope atomics measured write-through at 32B/op (~0.9 TB/s
//   cap; sector padding changed nothing). Fix: XCD-private histogram + CSR
//   replicas updated with workgroup-scope (L2-cached) atomics, XCD identified
//   via s_getreg(HW_REG_XCC_ID). k_finish sums replicas + compacts the 8 col
//   slices into the dense [N][48] CSR. Device-atomic fallback if ws too small.

typedef __bf16 bf16x8 __attribute__((ext_vector_type(8)));
typedef float f32x4 __attribute__((ext_vector_type(4)));

#define PAD 48    // max in-degree ~38 for E=1.6M,N=100K
#define PADX 24   // per-(node,XCD) slots: Binomial(38,~1/8) tail @24 ~ 1e-10
#define NXCD 8

__device__ inline unsigned short f2bf(float f) {
  unsigned u = __float_as_uint(f);
  u += 0x7fffu + ((u >> 16) & 1u);  // RNE
  return (unsigned short)(u >> 16);
}
__device__ inline float2 bfpair(unsigned u) {
  float2 r;
  r.x = __uint_as_float(u << 16);
  r.y = __uint_as_float(u & 0xffff0000u);
  return r;
}

__device__ inline int xcc_id() {
  int x;
  asm("s_getreg_b32 %0, hwreg(20, 0, 4)" : "=s"(x));  // HW_REG_XCC_ID
  return x & (NXCD - 1);
}

__device__ inline int l2add(int* p, int v) {
  // workgroup-scope: cached RMW in the XCD-local TCC (no fabric write-through).
  return __hip_atomic_fetch_add(p, v, __ATOMIC_RELAXED, __HIP_MEMORY_SCOPE_WORKGROUP);
}

// ---------------- full path: XCD-replicated build ----------------
__global__ __launch_bounds__(256) void k_fill_l2(const int* __restrict__ src,
                                                 const int* __restrict__ dst,
                                                 int* __restrict__ degR,
                                                 int* __restrict__ cntR,
                                                 int* __restrict__ colR,
                                                 int E, int N) {
  const int xc = xcc_id();
  int* degS = degR + (size_t)xc * N;
  int* cntS = cntR + (size_t)xc * N;
  int* colS = colR + (size_t)xc * N * PADX;
  int t = blockIdx.x * 256 + threadIdx.x;
  int e0 = t * 4;
  if (e0 >= E) return;
  if (e0 + 3 < E) {
    int4 s4 = *(const int4*)(src + e0);
    int4 d4 = *(const int4*)(dst + e0);
    int ss[4] = {s4.x, s4.y, s4.z, s4.w};
    int dd[4] = {d4.x, d4.y, d4.z, d4.w};
#pragma unroll
    for (int k = 0; k < 4; k++) {
      l2add(&degS[ss[k]], 1);
      int pos = l2add(&cntS[dd[k]], 1);
      if (pos < PADX) colS[dd[k] * PADX + pos] = ss[k];
    }
  } else {
    for (int e = e0; e < E; e++) {
      int s = src[e], d = dst[e];
      l2add(&degS[s], 1);
      int pos = l2add(&cntS[d], 1);
      if (pos < PADX) colS[d * PADX + pos] = s;
    }
  }
}

// sum replicas -> norms; compact 8 col slices -> col[N][PAD]; inv perm.
__global__ __launch_bounds__(256) void k_finish_full(const int* __restrict__ degR,
                                                     const int* __restrict__ cntR,
                                                     const int* __restrict__ colR,
                                                     const int* __restrict__ perm,
                                                     float* __restrict__ norm_o,
                                                     float* __restrict__ norm_i,
                                                     int* __restrict__ deg_d,
                                                     int* __restrict__ inv,
                                                     int* __restrict__ col, int N) {
  int i = blockIdx.x * 256 + threadIdx.x;
  if (i >= N) return;
  int a = 0, traw = 0;
  int cs[NXCD];
#pragma unroll
  for (int x = 0; x < NXCD; x++) {
    a += degR[(size_t)x * N + i];
    int c = cntR[(size_t)x * N + i];
    traw += c;
    cs[x] = (c > PADX) ? PADX : c;
  }
  int* cb = col + (size_t)i * PAD;
  int o = 0;
  for (int x = 0; x < NXCD; x++) {
    const int* sb = colR + ((size_t)x * N + i) * PADX;
    int c = cs[x];
    if (o + c > PAD) c = PAD - o;
    for (int j = 0; j < c; j++) cb[o + j] = sb[j];
    o += c;
  }
  deg_d[i] = o;
  int aa = (a < 1) ? 1 : a;
  int bb = (traw < 1) ? 1 : traw;
  norm_o[i] = rsqrtf((float)aa);
  norm_i[i] = rsqrtf((float)bb);
  inv[perm[i]] = i;  // perm is a bijection
}

// ---------------- fallback path: proven device-scope build ----------------
__global__ __launch_bounds__(256) void k_fill_dev(const int* __restrict__ src,
                                                  const int* __restrict__ dst,
                                                  int* __restrict__ deg_s,
                                                  int* __restrict__ cnt,
                                                  int* __restrict__ col, int E) {
  int t = blockIdx.x * 256 + threadIdx.x;
  int e0 = t * 4;
  if (e0 >= E) return;
  int e1 = (e0 + 4 < E) ? e0 + 4 : E;
  for (int e = e0; e < e1; e++) {
    int s = src[e], d = dst[e];
    atomicAdd(&deg_s[s], 1);
    int pos = atomicAdd(&cnt[d], 1);
    if (pos < PAD) col[(size_t)d * PAD + pos] = s;
  }
}

__global__ __launch_bounds__(256) void k_finish_dev(const int* __restrict__ deg_s,
                                                    const int* __restrict__ cnt,
                                                    const int* __restrict__ perm,
                                                    float* __restrict__ norm_o,
                                                    float* __restrict__ norm_i,
                                                    int* __restrict__ deg_d,
                                                    int* __restrict__ inv, int N) {
  int i = blockIdx.x * 256 + threadIdx.x;
  if (i >= N) return;
  int a = deg_s[i]; if (a < 1) a = 1;
  int b = cnt[i];
  deg_d[i] = (b > PAD) ? PAD : b;
  if (b < 1) b = 1;
  norm_o[i] = rsqrtf((float)a);
  norm_i[i] = rsqrtf((float)b);
  inv[perm[i]] = i;
}

// ---------------- W -> WT bf16 [128][512] ----------------
__global__ __launch_bounds__(256) void k_castw(const float* __restrict__ W,
                                               unsigned short* __restrict__ WT) {
  int i = blockIdx.x * 256 + threadIdx.x;  // i < 512*128
  int k = i >> 7;
  int n = i & 127;
  WT[n * 512 + k] = f2bf(W[i]);
}

// ---------------- GEMM: raw = x[N,512](f32) @ W; dual-scaled epilogue -------
// BM=64, BN=128, BK=32; 256 threads = 4 waves. MFMA 16x16x32 bf16.
// HH row layout [h1[128] | h2[128]]:
//   h1[r] = raw[r]*norm_o[r];  h2[q] = raw[r]*norm_o[q], q=inv[r].
#define AS_STRIDE 40
__global__ __launch_bounds__(256) void k_gemm(const float* __restrict__ X,
                                              const unsigned short* __restrict__ WT,
                                              const float* __restrict__ norm_o,
                                              const int* __restrict__ inv,
                                              unsigned short* __restrict__ HH, int M) {
  __shared__ __align__(16) unsigned short smem[8192];
  unsigned short* As = smem;                   // [64][AS_STRIDE]
  unsigned short* Bs = smem + 64 * AS_STRIDE;  // [128][AS_STRIDE]

  const int tid = threadIdx.x;
  const int wave = tid >> 6;
  const int lane = tid & 63;
  const int m = lane & 15;
  const int quad = lane >> 4;
  const int block_row = blockIdx.x * 64;

  f32x4 acc[8];
#pragma unroll
  for (int t = 0; t < 8; t++) acc[t] = (f32x4){0.f, 0.f, 0.f, 0.f};

  for (int k0 = 0; k0 < 512; k0 += 32) {
#pragma unroll
    for (int it = 0; it < 2; it++) {
      int idx = tid + it * 256;
      int row = idx >> 3;
      int kc = (idx & 7) * 4;
      int gr = block_row + row;
      float4 v = make_float4(0.f, 0.f, 0.f, 0.f);
      if (gr < M) v = *(const float4*)(X + (size_t)gr * 512 + k0 + kc);
      ushort4 b;
      b.x = f2bf(v.x); b.y = f2bf(v.y); b.z = f2bf(v.z); b.w = f2bf(v.w);
      *(ushort4*)&As[row * AS_STRIDE + kc] = b;
    }
#pragma unroll
    for (int it = 0; it < 2; it++) {
      int idx = tid + it * 256;
      int n = idx >> 2;
      int kc = (idx & 3) * 8;
      *(int4*)&Bs[n * AS_STRIDE + kc] = *(const int4*)(WT + (size_t)n * 512 + k0 + kc);
    }
    __syncthreads();

    bf16x8 a = *(bf16x8*)&As[(wave * 16 + m) * AS_STRIDE + quad * 8];
#pragma unroll
    for (int t = 0; t < 8; t++) {
      bf16x8 b = *(bf16x8*)&Bs[(t * 16 + m) * AS_STRIDE + quad * 8];
      acc[t] = __builtin_amdgcn_mfma_f32_16x16x32_bf16(a, b, acc[t], 0, 0, 0);
    }
    __syncthreads();
  }

  float no1[4], no2[4];
#pragma unroll
  for (int r = 0; r < 4; r++) {
    int rr = block_row + wave * 16 + quad * 4 + r;
    no1[r] = 0.f;
    no2[r] = 0.f;
    if (rr < M) {
      no1[r] = norm_o[rr];
      no2[r] = norm_o[inv[rr]];
    }
  }

  // pass 1: h1 -> HH[gr][0:128]
#pragma unroll
  for (int t = 0; t < 8; t++) {
    int c = t * 16 + m;
#pragma unroll
    for (int r = 0; r < 4; r++) {
      int row = wave * 16 + quad * 4 + r;
      smem[row * 128 + c] = f2bf(acc[t][r] * no1[r]);
    }
  }
  __syncthreads();
#pragma unroll
  for (int it = 0; it < 4; it++) {
    int idx = tid + it * 256;
    int row = idx >> 4;
    int c8 = (idx & 15) * 8;
    int gr = block_row + row;
    if (gr < M)
      *(int4*)(HH + (size_t)gr * 256 + c8) = *(int4*)&smem[row * 128 + c8];
  }
  __syncthreads();

  // pass 2: h2 -> HH[inv[gr]][128:256]
#pragma unroll
  for (int t = 0; t < 8; t++) {
    int c = t * 16 + m;
#pragma unroll
    for (int r = 0; r < 4; r++) {
      int row = wave * 16 + quad * 4 + r;
      smem[row * 128 + c] = f2bf(acc[t][r] * no2[r]);
    }
  }
  __syncthreads();
#pragma unroll
  for (int it = 0; it < 4; it++) {
    int idx = tid + it * 256;
    int row = idx >> 4;
    int c8 = (idx & 15) * 8;
    int gr = block_row + row;
    if (gr < M) {
      int q = inv[gr];
      *(int4*)(HH + (size_t)q * 256 + 128 + c8) = *(int4*)&smem[row * 128 + c8];
    }
  }
}

// ---------------- folded MLP vector ----------------
__global__ __launch_bounds__(128) void k_wsum(const float* __restrict__ mlpW,
                                              const float* __restrict__ mlpb,
                                              float* __restrict__ wsum,
                                              float* __restrict__ bsum) {
  __shared__ float sb[128];
  int k = threadIdx.x;
  float s = 0.f;
  for (int j = 0; j < 128; j++) s += mlpW[k * 128 + j];
  wsum[k] = s;
  sb[k] = mlpb[k];
  __syncthreads();
  for (int off = 64; off > 0; off >>= 1) {
    if (k < off) sb[k] += sb[k + off];
    __syncthreads();
  }
  if (k == 0) bsum[0] = sb[0];
}

// ---------------- aggregation + fused epilogue ----------------
// one wave per dst node; quad g handles edge j0+g; sub-lane sl owns features
// 8sl..8sl+7. Each edge = ONE contiguous 512B HH row (h1 @ sl*8, h2 @ 128+sl*8).
__global__ __launch_bounds__(256) void k_agg(const unsigned short* __restrict__ HH,
                                             const int* __restrict__ deg_d,
                                             const int* __restrict__ col,
                                             const float* __restrict__ norm_i,
                                             const float* __restrict__ bias,
                                             const float* __restrict__ alpha,
                                             const float* __restrict__ wsum,
                                             const float* __restrict__ bsum,
                                             float* __restrict__ out, int N) {
  int wave = (blockIdx.x * 256 + threadIdx.x) >> 6;
  int lane = threadIdx.x & 63;
  if (wave >= N) return;
  const int g = lane >> 4;
  const int sl = lane & 15;

  int cl = deg_d[wave];
  const int* cbase = col + (size_t)wave * PAD;

  float a1[8], a2[8];
#pragma unroll
  for (int i = 0; i < 8; i++) { a1[i] = 0.f; a2[i] = 0.f; }

  for (int j0 = 0; j0 < cl; j0 += 4) {
    int j = j0 + g;
    int je = (j < cl) ? j : cl - 1;
    int s = cbase[je];
    float mk = (j < cl) ? 1.f : 0.f;
    const unsigned short* rp = HH + (size_t)s * 256 + sl * 8;
    int4 r1 = *(const int4*)rp;
    int4 r2 = *(const int4*)(rp + 128);
    const unsigned* u1 = (const unsigned*)&r1;
    const unsigned* u2 = (const unsigned*)&r2;
#pragma unroll
    for (int q = 0; q < 4; q++) {
      float2 v1 = bfpair(u1[q]);
      float2 v2 = bfpair(u2[q]);
      a1[2 * q]     = fmaf(v1.x, mk, a1[2 * q]);
      a1[2 * q + 1] = fmaf(v1.y, mk, a1[2 * q + 1]);
      a2[2 * q]     = fmaf(v2.x, mk, a2[2 * q]);
      a2[2 * q + 1] = fmaf(v2.y, mk, a2[2 * q + 1]);
    }
  }

#pragma unroll
  for (int i = 0; i < 8; i++) {
    a1[i] += __shfl_xor(a1[i], 16);
    a1[i] += __shfl_xor(a1[i], 32);
    a2[i] += __shfl_xor(a2[i], 16);
    a2[i] += __shfl_xor(a2[i], 32);
  }

  float ni = norm_i[wave];
  float4 bb0 = ((const float4*)bias)[sl * 2];
  float4 bb1 = ((const float4*)bias)[sl * 2 + 1];
  float4 al0 = ((const float4*)alpha)[sl * 2];
  float4 al1 = ((const float4*)alpha)[sl * 2 + 1];
  float4 ws0 = ((const float4*)wsum)[sl * 2];
  float4 ws1 = ((const float4*)wsum)[sl * 2 + 1];
  float bs = bsum[0];
  float bb[8] = {bb0.x, bb0.y, bb0.z, bb0.w, bb1.x, bb1.y, bb1.z, bb1.w};
  float al[8] = {al0.x, al0.y, al0.z, al0.w, al1.x, al1.y, al1.z, al1.w};
  float wsv[8] = {ws0.x, ws0.y, ws0.z, ws0.w, ws1.x, ws1.y, ws1.z, ws1.w};

  float p1 = 0.f, p2 = 0.f;
#pragma unroll
  for (int i = 0; i < 8; i++) {
    float g1 = a1[i] * ni + bb[i];
    float g2 = a2[i] * ni + bb[i];
    g1 = (g1 >= 0.f) ? g1 : al[i] * g1;
    g2 = (g2 >= 0.f) ? g2 : al[i] * g2;
    p1 = fmaf(g1, wsv[i], p1);
    p2 = fmaf(g2, wsv[i], p2);
  }
#pragma unroll
  for (int off = 8; off > 0; off >>= 1) {
    p1 += __shfl_down(p1, off);
    p2 += __shfl_down(p2, off);
  }
  if (lane == 0) {
    out[wave] = p1 + bs;
    out[N + wave] = p2 + bs;
  }
}

// ---------------- launch ----------------

extern "C" void kernel_launch(void* const* d_in, const int* in_sizes, int n_in,
                              void* d_out, int out_size, void* d_ws, size_t ws_size,
                              hipStream_t stream) {
  const float* x = (const float*)d_in[0];
  const int* src = (const int*)d_in[1];
  const int* dst = (const int*)d_in[2];
  const int* perm = (const int*)d_in[3];
  const float* W = (const float*)d_in[4];
  const float* bias = (const float*)d_in[5];
  const float* alpha = (const float*)d_in[6];
  const float* mlpW = (const float*)d_in[7];
  const float* mlpb = (const float*)d_in[8];

  const int E = in_sizes[1];
  const int N = in_sizes[3];
  float* out = (float*)d_out;

  char* ws = (char*)d_ws;
  size_t off = 0;
  auto alloc = [&](size_t bytes) -> void* {
    void* p = ws + off;
    off = (off + bytes + 255) & ~(size_t)255;
    return p;
  };

  // common
  unsigned short* HH = (unsigned short*)alloc((size_t)N * 256 * sizeof(unsigned short));
  int* col = (int*)alloc((size_t)N * PAD * sizeof(int));
  unsigned short* WT = (unsigned short*)alloc(512 * 128 * sizeof(unsigned short));
  float* norm_o = (float*)alloc((size_t)N * sizeof(float));
  float* norm_i = (float*)alloc((size_t)N * sizeof(float));
  int* inv = (int*)alloc((size_t)N * sizeof(int));
  int* deg_d = (int*)alloc((size_t)N * sizeof(int));
  float* wsum = (float*)alloc(512);
  float* bsum = (float*)alloc(256);
  size_t common = off;

  // full-path extra: 8x replicas
  size_t need_full = common + (size_t)NXCD * N * sizeof(int) * 2 +
                     (size_t)NXCD * N * PADX * sizeof(int) + 4096;
  bool full = (ws_size == 0) || (ws_size >= need_full);

  const int nbN = (N + 255) / 256;
  const int nbE4 = ((E + 3) / 4 + 255) / 256;

  k_castw<<<512 * 128 / 256, 256, 0, stream>>>(W, WT);
  k_wsum<<<1, 128, 0, stream>>>(mlpW, mlpb, wsum, bsum);

  if (full) {
    int* degR = (int*)alloc((size_t)NXCD * N * sizeof(int));
    int* cntR = (int*)alloc((size_t)NXCD * N * sizeof(int));
    int* colR = (int*)alloc((size_t)NXCD * N * PADX * sizeof(int));
    hipMemsetAsync(degR, 0, (size_t)NXCD * N * sizeof(int), stream);
    hipMemsetAsync(cntR, 0, (size_t)NXCD * N * sizeof(int), stream);
    k_fill_l2<<<nbE4, 256, 0, stream>>>(src, dst, degR, cntR, colR, E, N);
    k_finish_full<<<nbN, 256, 0, stream>>>(degR, cntR, colR, perm, norm_o,
                                           norm_i, deg_d, inv, col, N);
  } else {
    int* deg_s = (int*)alloc((size_t)N * sizeof(int));
    int* cnt = (int*)alloc((size_t)N * sizeof(int));
    hipMemsetAsync(deg_s, 0, (size_t)N * sizeof(int), stream);
    hipMemsetAsync(cnt, 0, (size_t)N * sizeof(int), stream);
    k_fill_dev<<<nbE4, 256, 0, stream>>>(src, dst, deg_s, cnt, col, E);
    k_finish_dev<<<nbN, 256, 0, stream>>>(deg_s, cnt, perm, norm_o, norm_i,
                                          deg_d, inv, N);
  }

  k_gemm<<<(N + 63) / 64, 256, 0, stream>>>(x, WT, norm_o, inv, HH, N);
  k_agg<<<(N + 3) / 4, 256, 0, stream>>>(HH, deg_d, col, norm_i,
                                         bias, alpha, wsum, bsum, out, N);
}

// Round 3
// 531.281 us; speedup vs baseline: 1.2422x; 1.2422x over previous
//
#include <hip/hip_runtime.h>

// DinkNet: 2x GraphConv(512->128) encoders (clean + row-permuted) + PReLU,
// folded MLP (rowsum trick) -> logit[2N].
//
// Identities:  (x[perm])@W = (x@W)[perm]  -> one GEMM
//              (z@mlpW+mlpb).sum(1) = z . rowsum(mlpW) + sum(mlpb)
// Round 6: scattered device atomics are write-through (~0.92 TB/s, scope
//   flags irrelevant - measured twice). Replace the atomic CSR build with a
//   two-level binned build: k_bin (LDS per-block bucket counts + one global
//   reservation atomic per (block,bucket) + compact record scatter, all
//   L2-cacheable), then k_csr / k_shist do per-bucket LDS-atomic expansion
//   into col[N][48] / degree histograms with fully coalesced epilogues.

typedef __bf16 bf16x8 __attribute__((ext_vector_type(8)));
typedef float f32x4 __attribute__((ext_vector_type(4)));

#define PAD 48     // max in-degree ~38 for E=1.6M,N=100K
#define NBMAX 256  // max buckets (512 nodes each) -> N <= 131072
#define EPB 4096   // edges per k_bin block

__device__ inline unsigned short f2bf(float f) {
  unsigned u = __float_as_uint(f);
  u += 0x7fffu + ((u >> 16) & 1u);  // RNE
  return (unsigned short)(u >> 16);
}
__device__ inline float2 bfpair(unsigned u) {
  float2 r;
  r.x = __uint_as_float(u << 16);
  r.y = __uint_as_float(u & 0xffff0000u);
  return r;
}

// ---------------- pass 1: bin edges by dst-bucket and src-bucket ----------
// record for CSR: (src<<9)|(dst&511)  (src<2^17, 9 low dst bits -> 26 bits)
// record for src-hist: src&511 (ushort)
__global__ __launch_bounds__(256) void k_bin(const int* __restrict__ src,
                                             const int* __restrict__ dst,
                                             int* __restrict__ gCntD,
                                             int* __restrict__ gCntS,
                                             int* __restrict__ dstbin,
                                             unsigned short* __restrict__ srcbin,
                                             int E, int NB, int CAP) {
  __shared__ int2 stage[EPB];
  __shared__ int cntD[NBMAX], cntS[NBMAX], baseD[NBMAX], baseS[NBMAX];
  const int tid = threadIdx.x;
  const int e0 = blockIdx.x * EPB;
  const int nloc = min(EPB, E - e0);

  for (int b = tid; b < NB; b += 256) { cntD[b] = 0; cntS[b] = 0; }
  __syncthreads();

#pragma unroll
  for (int it = 0; it < EPB / 256; ++it) {
    int i = it * 256 + tid;
    if (i < nloc) {
      int s = src[e0 + i];
      int d = dst[e0 + i];
      stage[i] = make_int2(s, d);
      atomicAdd(&cntD[d >> 9], 1);
      atomicAdd(&cntS[s >> 9], 1);
    }
  }
  __syncthreads();

  for (int b = tid; b < NB; b += 256) {
    baseD[b] = atomicAdd(&gCntD[b], cntD[b]);
    baseS[b] = atomicAdd(&gCntS[b], cntS[b]);
    cntD[b] = 0;
    cntS[b] = 0;
  }
  __syncthreads();

#pragma unroll
  for (int it = 0; it < EPB / 256; ++it) {
    int i = it * 256 + tid;
    if (i < nloc) {
      int2 sd = stage[i];
      int s = sd.x, d = sd.y;
      int bd = d >> 9;
      int p = atomicAdd(&cntD[bd], 1) + baseD[bd];
      if (p < CAP) dstbin[(size_t)bd * CAP + p] = (s << 9) | (d & 511);
      int bs = s >> 9;
      int q = atomicAdd(&cntS[bs], 1) + baseS[bs];
      if (q < CAP) srcbin[(size_t)bs * CAP + q] = (unsigned short)(s & 511);
    }
  }
}

// ---------------- pass 2a: per-bucket CSR expansion ----------------
__global__ __launch_bounds__(256) void k_csr(const int* __restrict__ gCntD,
                                             const int* __restrict__ dstbin,
                                             int* __restrict__ col,
                                             int* __restrict__ deg_d,
                                             float* __restrict__ norm_i,
                                             int N, int CAP) {
  __shared__ int cnt[512];
  const int b = blockIdx.x;
  const int tid = threadIdx.x;
  cnt[tid] = 0;
  cnt[tid + 256] = 0;
  __syncthreads();
  int cb = gCntD[b];
  if (cb > CAP) cb = CAP;
  const int* bin = dstbin + (size_t)b * CAP;
  for (int i = tid; i < cb; i += 256) {
    int rec = bin[i];
    int d9 = rec & 511;
    int s = rec >> 9;
    int pos = atomicAdd(&cnt[d9], 1);
    if (pos < PAD) col[((size_t)b * 512 + d9) * PAD + pos] = s;
  }
  __syncthreads();
  for (int t = tid; t < 512; t += 256) {
    int i = b * 512 + t;
    if (i < N) {
      int c = cnt[t];
      deg_d[i] = (c > PAD) ? PAD : c;
      norm_i[i] = rsqrtf((float)((c < 1) ? 1 : c));
    }
  }
}

// ---------------- pass 2b: per-bucket src histogram + inv perm -------------
__global__ __launch_bounds__(256) void k_shist(const int* __restrict__ gCntS,
                                               const unsigned short* __restrict__ srcbin,
                                               const int* __restrict__ perm,
                                               float* __restrict__ norm_o,
                                               int* __restrict__ inv,
                                               int N, int CAP) {
  __shared__ int hist[512];
  const int b = blockIdx.x;
  const int tid = threadIdx.x;
  hist[tid] = 0;
  hist[tid + 256] = 0;
  __syncthreads();
  int cb = gCntS[b];
  if (cb > CAP) cb = CAP;
  const unsigned short* bin = srcbin + (size_t)b * CAP;
  for (int i = tid; i < cb; i += 256) {
    atomicAdd(&hist[bin[i]], 1);
  }
  __syncthreads();
  for (int t = tid; t < 512; t += 256) {
    int i = b * 512 + t;
    if (i < N) {
      int h = hist[t];
      norm_o[i] = rsqrtf((float)((h < 1) ? 1 : h));
      inv[perm[i]] = i;  // perm is a bijection
    }
  }
}

// ---------------- fallback path: proven device-scope build ----------------
__global__ __launch_bounds__(256) void k_fill_dev(const int* __restrict__ src,
                                                  const int* __restrict__ dst,
                                                  int* __restrict__ deg_s,
                                                  int* __restrict__ cnt,
                                                  int* __restrict__ col, int E) {
  int t = blockIdx.x * 256 + threadIdx.x;
  int e0 = t * 4;
  if (e0 >= E) return;
  int e1 = (e0 + 4 < E) ? e0 + 4 : E;
  for (int e = e0; e < e1; e++) {
    int s = src[e], d = dst[e];
    atomicAdd(&deg_s[s], 1);
    int pos = atomicAdd(&cnt[d], 1);
    if (pos < PAD) col[(size_t)d * PAD + pos] = s;
  }
}

__global__ __launch_bounds__(256) void k_finish_dev(const int* __restrict__ deg_s,
                                                    const int* __restrict__ cnt,
                                                    const int* __restrict__ perm,
                                                    float* __restrict__ norm_o,
                                                    float* __restrict__ norm_i,
                                                    int* __restrict__ deg_d,
                                                    int* __restrict__ inv, int N) {
  int i = blockIdx.x * 256 + threadIdx.x;
  if (i >= N) return;
  int a = deg_s[i]; if (a < 1) a = 1;
  int b = cnt[i];
  deg_d[i] = (b > PAD) ? PAD : b;
  if (b < 1) b = 1;
  norm_o[i] = rsqrtf((float)a);
  norm_i[i] = rsqrtf((float)b);
  inv[perm[i]] = i;
}

// ---------------- W -> WT bf16 [128][512] ----------------
__global__ __launch_bounds__(256) void k_castw(const float* __restrict__ W,
                                               unsigned short* __restrict__ WT) {
  int i = blockIdx.x * 256 + threadIdx.x;  // i < 512*128
  int k = i >> 7;
  int n = i & 127;
  WT[n * 512 + k] = f2bf(W[i]);
}

// ---------------- GEMM: raw = x[N,512](f32) @ W; dual-scaled epilogue -------
// BM=64, BN=128, BK=32; 256 threads = 4 waves. MFMA 16x16x32 bf16.
// HH row layout [h1[128] | h2[128]]:
//   h1[r] = raw[r]*norm_o[r];  h2[q] = raw[r]*norm_o[q], q=inv[r].
#define AS_STRIDE 40
__global__ __launch_bounds__(256) void k_gemm(const float* __restrict__ X,
                                              const unsigned short* __restrict__ WT,
                                              const float* __restrict__ norm_o,
                                              const int* __restrict__ inv,
                                              unsigned short* __restrict__ HH, int M) {
  __shared__ __align__(16) unsigned short smem[8192];
  unsigned short* As = smem;                   // [64][AS_STRIDE]
  unsigned short* Bs = smem + 64 * AS_STRIDE;  // [128][AS_STRIDE]

  const int tid = threadIdx.x;
  const int wave = tid >> 6;
  const int lane = tid & 63;
  const int m = lane & 15;
  const int quad = lane >> 4;
  const int block_row = blockIdx.x * 64;

  f32x4 acc[8];
#pragma unroll
  for (int t = 0; t < 8; t++) acc[t] = (f32x4){0.f, 0.f, 0.f, 0.f};

  for (int k0 = 0; k0 < 512; k0 += 32) {
#pragma unroll
    for (int it = 0; it < 2; it++) {
      int idx = tid + it * 256;
      int row = idx >> 3;
      int kc = (idx & 7) * 4;
      int gr = block_row + row;
      float4 v = make_float4(0.f, 0.f, 0.f, 0.f);
      if (gr < M) v = *(const float4*)(X + (size_t)gr * 512 + k0 + kc);
      ushort4 b;
      b.x = f2bf(v.x); b.y = f2bf(v.y); b.z = f2bf(v.z); b.w = f2bf(v.w);
      *(ushort4*)&As[row * AS_STRIDE + kc] = b;
    }
#pragma unroll
    for (int it = 0; it < 2; it++) {
      int idx = tid + it * 256;
      int n = idx >> 2;
      int kc = (idx & 3) * 8;
      *(int4*)&Bs[n * AS_STRIDE + kc] = *(const int4*)(WT + (size_t)n * 512 + k0 + kc);
    }
    __syncthreads();

    bf16x8 a = *(bf16x8*)&As[(wave * 16 + m) * AS_STRIDE + quad * 8];
#pragma unroll
    for (int t = 0; t < 8; t++) {
      bf16x8 b = *(bf16x8*)&Bs[(t * 16 + m) * AS_STRIDE + quad * 8];
      acc[t] = __builtin_amdgcn_mfma_f32_16x16x32_bf16(a, b, acc[t], 0, 0, 0);
    }
    __syncthreads();
  }

  float no1[4], no2[4];
#pragma unroll
  for (int r = 0; r < 4; r++) {
    int rr = block_row + wave * 16 + quad * 4 + r;
    no1[r] = 0.f;
    no2[r] = 0.f;
    if (rr < M) {
      no1[r] = norm_o[rr];
      no2[r] = norm_o[inv[rr]];
    }
  }

  // pass 1: h1 -> HH[gr][0:128]
#pragma unroll
  for (int t = 0; t < 8; t++) {
    int c = t * 16 + m;
#pragma unroll
    for (int r = 0; r < 4; r++) {
      int row = wave * 16 + quad * 4 + r;
      smem[row * 128 + c] = f2bf(acc[t][r] * no1[r]);
    }
  }
  __syncthreads();
#pragma unroll
  for (int it = 0; it < 4; it++) {
    int idx = tid + it * 256;
    int row = idx >> 4;
    int c8 = (idx & 15) * 8;
    int gr = block_row + row;
    if (gr < M)
      *(int4*)(HH + (size_t)gr * 256 + c8) = *(int4*)&smem[row * 128 + c8];
  }
  __syncthreads();

  // pass 2: h2 -> HH[inv[gr]][128:256]
#pragma unroll
  for (int t = 0; t < 8; t++) {
    int c = t * 16 + m;
#pragma unroll
    for (int r = 0; r < 4; r++) {
      int row = wave * 16 + quad * 4 + r;
      smem[row * 128 + c] = f2bf(acc[t][r] * no2[r]);
    }
  }
  __syncthreads();
#pragma unroll
  for (int it = 0; it < 4; it++) {
    int idx = tid + it * 256;
    int row = idx >> 4;
    int c8 = (idx & 15) * 8;
    int gr = block_row + row;
    if (gr < M) {
      int q = inv[gr];
      *(int4*)(HH + (size_t)q * 256 + 128 + c8) = *(int4*)&smem[row * 128 + c8];
    }
  }
}

// ---------------- folded MLP vector ----------------
__global__ __launch_bounds__(128) void k_wsum(const float* __restrict__ mlpW,
                                              const float* __restrict__ mlpb,
                                              float* __restrict__ wsum,
                                              float* __restrict__ bsum) {
  __shared__ float sb[128];
  int k = threadIdx.x;
  float s = 0.f;
  for (int j = 0; j < 128; j++) s += mlpW[k * 128 + j];
  wsum[k] = s;
  sb[k] = mlpb[k];
  __syncthreads();
  for (int off = 64; off > 0; off >>= 1) {
    if (k < off) sb[k] += sb[k + off];
    __syncthreads();
  }
  if (k == 0) bsum[0] = sb[0];
}

// ---------------- aggregation + fused epilogue ----------------
// one wave per dst node; quad g handles edge j0+g; sub-lane sl owns features
// 8sl..8sl+7. Each edge = ONE contiguous 512B HH row (h1 @ sl*8, h2 @ 128+sl*8).
__global__ __launch_bounds__(256) void k_agg(const unsigned short* __restrict__ HH,
                                             const int* __restrict__ deg_d,
                                             const int* __restrict__ col,
                                             const float* __restrict__ norm_i,
                                             const float* __restrict__ bias,
                                             const float* __restrict__ alpha,
                                             const float* __restrict__ wsum,
                                             const float* __restrict__ bsum,
                                             float* __restrict__ out, int N) {
  int wave = (blockIdx.x * 256 + threadIdx.x) >> 6;
  int lane = threadIdx.x & 63;
  if (wave >= N) return;
  const int g = lane >> 4;
  const int sl = lane & 15;

  int cl = deg_d[wave];
  const int* cbase = col + (size_t)wave * PAD;

  float a1[8], a2[8];
#pragma unroll
  for (int i = 0; i < 8; i++) { a1[i] = 0.f; a2[i] = 0.f; }

  for (int j0 = 0; j0 < cl; j0 += 4) {
    int j = j0 + g;
    int je = (j < cl) ? j : cl - 1;
    int s = cbase[je];
    float mk = (j < cl) ? 1.f : 0.f;
    const unsigned short* rp = HH + (size_t)s * 256 + sl * 8;
    int4 r1 = *(const int4*)rp;
    int4 r2 = *(const int4*)(rp + 128);
    const unsigned* u1 = (const unsigned*)&r1;
    const unsigned* u2 = (const unsigned*)&r2;
#pragma unroll
    for (int q = 0; q < 4; q++) {
      float2 v1 = bfpair(u1[q]);
      float2 v2 = bfpair(u2[q]);
      a1[2 * q]     = fmaf(v1.x, mk, a1[2 * q]);
      a1[2 * q + 1] = fmaf(v1.y, mk, a1[2 * q + 1]);
      a2[2 * q]     = fmaf(v2.x, mk, a2[2 * q]);
      a2[2 * q + 1] = fmaf(v2.y, mk, a2[2 * q + 1]);
    }
  }

#pragma unroll
  for (int i = 0; i < 8; i++) {
    a1[i] += __shfl_xor(a1[i], 16);
    a1[i] += __shfl_xor(a1[i], 32);
    a2[i] += __shfl_xor(a2[i], 16);
    a2[i] += __shfl_xor(a2[i], 32);
  }

  float ni = norm_i[wave];
  float4 bb0 = ((const float4*)bias)[sl * 2];
  float4 bb1 = ((const float4*)bias)[sl * 2 + 1];
  float4 al0 = ((const float4*)alpha)[sl * 2];
  float4 al1 = ((const float4*)alpha)[sl * 2 + 1];
  float4 ws0 = ((const float4*)wsum)[sl * 2];
  float4 ws1 = ((const float4*)wsum)[sl * 2 + 1];
  float bs = bsum[0];
  float bb[8] = {bb0.x, bb0.y, bb0.z, bb0.w, bb1.x, bb1.y, bb1.z, bb1.w};
  float al[8] = {al0.x, al0.y, al0.z, al0.w, al1.x, al1.y, al1.z, al1.w};
  float wsv[8] = {ws0.x, ws0.y, ws0.z, ws0.w, ws1.x, ws1.y, ws1.z, ws1.w};

  float p1 = 0.f, p2 = 0.f;
#pragma unroll
  for (int i = 0; i < 8; i++) {
    float g1 = a1[i] * ni + bb[i];
    float g2 = a2[i] * ni + bb[i];
    g1 = (g1 >= 0.f) ? g1 : al[i] * g1;
    g2 = (g2 >= 0.f) ? g2 : al[i] * g2;
    p1 = fmaf(g1, wsv[i], p1);
    p2 = fmaf(g2, wsv[i], p2);
  }
#pragma unroll
  for (int off = 8; off > 0; off >>= 1) {
    p1 += __shfl_down(p1, off);
    p2 += __shfl_down(p2, off);
  }
  if (lane == 0) {
    out[wave] = p1 + bs;
    out[N + wave] = p2 + bs;
  }
}

// ---------------- launch ----------------

extern "C" void kernel_launch(void* const* d_in, const int* in_sizes, int n_in,
                              void* d_out, int out_size, void* d_ws, size_t ws_size,
                              hipStream_t stream) {
  const float* x = (const float*)d_in[0];
  const int* src = (const int*)d_in[1];
  const int* dst = (const int*)d_in[2];
  const int* perm = (const int*)d_in[3];
  const float* W = (const float*)d_in[4];
  const float* bias = (const float*)d_in[5];
  const float* alpha = (const float*)d_in[6];
  const float* mlpW = (const float*)d_in[7];
  const float* mlpb = (const float*)d_in[8];

  const int E = in_sizes[1];
  const int N = in_sizes[3];
  float* out = (float*)d_out;

  char* ws = (char*)d_ws;
  size_t off = 0;
  auto alloc = [&](size_t bytes) -> void* {
    void* p = ws + off;
    off = (off + bytes + 255) & ~(size_t)255;
    return p;
  };

  // common
  unsigned short* HH = (unsigned short*)alloc((size_t)N * 256 * sizeof(unsigned short));
  int* col = (int*)alloc((size_t)N * PAD * sizeof(int));
  unsigned short* WT = (unsigned short*)alloc(512 * 128 * sizeof(unsigned short));
  float* norm_o = (float*)alloc((size_t)N * sizeof(float));
  float* norm_i = (float*)alloc((size_t)N * sizeof(float));
  int* inv = (int*)alloc((size_t)N * sizeof(int));
  int* deg_d = (int*)alloc((size_t)N * sizeof(int));
  float* wsum = (float*)alloc(512);
  float* bsum = (float*)alloc(256);
  size_t common = off;

  const int NB = (N + 511) >> 9;                        // 196 for N=100K
  const int meanB = (NB > 0) ? E / NB : 0;
  const int CAP = ((meanB * 5) / 4 + 1023) & ~1023;     // 10240 for this shape

  size_t need_binned = common + (size_t)NB * CAP * sizeof(int) +
                       (size_t)NB * CAP * sizeof(unsigned short) +
                       2 * (size_t)NBMAX * sizeof(int) + 4096;
  bool binned = (NB <= NBMAX) && ((ws_size == 0) || (ws_size >= need_binned));

  const int nbN = (N + 255) / 256;
  const int nbE4 = ((E + 3) / 4 + 255) / 256;

  k_castw<<<512 * 128 / 256, 256, 0, stream>>>(W, WT);
  k_wsum<<<1, 128, 0, stream>>>(mlpW, mlpb, wsum, bsum);

  if (binned) {
    int* dstbin = (int*)alloc((size_t)NB * CAP * sizeof(int));
    unsigned short* srcbin = (unsigned short*)alloc((size_t)NB * CAP * sizeof(unsigned short));
    int* gCntD = (int*)alloc((size_t)NBMAX * sizeof(int));
    int* gCntS = (int*)alloc((size_t)NBMAX * sizeof(int));
    hipMemsetAsync(gCntD, 0, (size_t)NBMAX * sizeof(int), stream);
    hipMemsetAsync(gCntS, 0, (size_t)NBMAX * sizeof(int), stream);
    const int nbBin = (E + EPB - 1) / EPB;
    k_bin<<<nbBin, 256, 0, stream>>>(src, dst, gCntD, gCntS, dstbin, srcbin,
                                     E, NB, CAP);
    k_csr<<<NB, 256, 0, stream>>>(gCntD, dstbin, col, deg_d, norm_i, N, CAP);
    k_shist<<<NB, 256, 0, stream>>>(gCntS, srcbin, perm, norm_o, inv, N, CAP);
  } else {
    int* deg_s = (int*)alloc((size_t)N * sizeof(int));
    int* cnt = (int*)alloc((size_t)N * sizeof(int));
    hipMemsetAsync(deg_s, 0, (size_t)N * sizeof(int), stream);
    hipMemsetAsync(cnt, 0, (size_t)N * sizeof(int), stream);
    k_fill_dev<<<nbE4, 256, 0, stream>>>(src, dst, deg_s, cnt, col, E);
    k_finish_dev<<<nbN, 256, 0, stream>>>(deg_s, cnt, perm, norm_o, norm_i,
                                          deg_d, inv, N);
  }

  k_gemm<<<(N + 63) / 64, 256, 0, stream>>>(x, WT, norm_o, inv, HH, N);
  k_agg<<<(N + 3) / 4, 256, 0, stream>>>(HH, deg_d, col, norm_i,
                                         bias, alpha, wsum, bsum, out, N);
}